// Round 18
// baseline (133.635 us; speedup 1.0000x reference)
//
#include <hip/hip_runtime.h>
#include <cmath>

#define BB   8
#define NPIX 256
#define MM   8192
#define NCP  24576
#define NCA  24576
#define EPSF 1e-16f

#define KC   32    // K-chunk (y's per chunk) = one MFMA K-step
#define TMB  128   // m's per block
#define NT   512   // threads per block (8 waves)

// ---- d_out layout (floats)
#define VIS_OFF    0
#define VISAMP_OFF (BB * 2 * MM)            // 131072
#define CPH_OFF    (VISAMP_OFF + BB * MM)   // 196608
#define LCA_OFF    (CPH_OFF + BB * NCP)     // 393216

typedef __bf16 bf16x8 __attribute__((ext_vector_type(8)));
typedef float  f32x4  __attribute__((ext_vector_type(4)));

// Window layout: element (row,k) -> (row>>4)*512 + (k>>3)*128 + (row&15)*8
// + (k&7). Staging writes and fragment reads: 16 B lane stride within each
// 16-lane phase -> 2-way bank aliasing only (free, m136).
// SESSION RULES (hard-won):
//  - no cross-kernel dataflow through d_ws (R5/R6); d_out is proven.
//  - acc = 128 AGPR + ~124 VGPR: needs the 256-reg budget (launch_bounds
//    2nd arg = 2). Tighter caps spill catastrophically (R8/R10).
//    WRITE_SIZE is the spill tripwire (768 KB = clean).
//  - NUMERICS: full 3-term split mandatory (R12: 2-term -> cphase 361 deg).
//  - R18: double-buffered LDS (128 KB), ONE barrier per chunk -> waves can
//    overlap staging VALU with MFMA across the block's 8 waves.
//  - residual ~57 us outside the vis kernel is harness-fixed (invariant
//    across gather rewrites R9/R11/R13); vis is the only lever.
#define WIDX(row, k8) (((row) >> 4) * 512 + (k8) * 128 + ((row) & 15) * 8)

// range reduction: theta == k*n (mod 2pi) in [-pi,pi] (keeps sincosf fast).
__device__ __forceinline__ float red2pi(float k, float n)
{
    const double t = (double)k * (double)n * 0.15915494309189535;  // /(2pi)
    const double f = t - rint(t);
    return (float)(f * 6.283185307179586);
}

// Block: 128 m's x 256 x's x 1 batch, 8 waves. Ev via rotor recurrences.
// 3-term split MFMA (hh, hl, lh) per plane. Double-buffered LDS pipeline.
__global__ __launch_bounds__(NT, 2)
void nufft_vis_mfma(const float* __restrict__ images,
                    const float* __restrict__ ktraj,
                    const float* __restrict__ pulsefac,
                    float* __restrict__ out)
{
    __shared__ __align__(16) __bf16 sArh[2][TMB * KC];   // 2 x 8 KB
    __shared__ __align__(16) __bf16 sArl[2][TMB * KC];
    __shared__ __align__(16) __bf16 sAih[2][TMB * KC];
    __shared__ __align__(16) __bf16 sAil[2][TMB * KC];
    __shared__ __align__(16) __bf16 sBh[2][NPIX * KC];   // 2 x 16 KB
    __shared__ __align__(16) __bf16 sBl[2][NPIX * KC];   // total 128 KB

    const int tid  = threadIdx.x;
    const int m0   = blockIdx.x * TMB;
    const int b    = blockIdx.y;
    const int lane = tid & 63;
    const int w    = tid >> 6;        // wave 0..7
    const int ln15 = lane & 15;
    const int q    = lane >> 4;       // k-octet 0..3

    // A staging: thread stages Ev row = tid&127, k-octet = tid>>7.
    const int arow = tid & 127;
    const int aoct = tid >> 7;        // 0..3
    const float kvm = ktraj[m0 + arow];
    float r1s, r1c, r32s, r32c, as_, ac_;
    sincosf(kvm, &r1s, &r1c);                          // rot1: |kvm| <= pi
    sincosf(red2pi(kvm, 32.0f), &r32s, &r32c);         // rot32
    sincosf(red2pi(kvm, (float)(aoct * 8 - 128)), &as_, &ac_);  // anchor @ y0=0
    float anr = ac_, ani = -as_;
    const int ao = WIDX(arow, aoct);

    // B staging: x = tid&255, y-octet pair = (tid>>8)*2 .. +1
    const int bx    = tid & 255;
    const int bhalf = tid >> 8;       // 0..1
    const float* imgb = images + b * NPIX * NPIX + bx;

    f32x4 acc[2][16];                 // [0]=real plane, [1]=imag plane
    #pragma unroll
    for (int rt = 0; rt < 2; ++rt)
        #pragma unroll
        for (int ct = 0; ct < 16; ++ct)
            acc[rt][ct] = (f32x4){0.f, 0.f, 0.f, 0.f};

    // stage chunk starting at y0 into buffer bu (advances anchor state)
    auto stage = [&](int y0, int bu) {
        {   // A: Ev[m0+arow, y0+8*aoct .. +8) via anchor + rot1 recurrence
            float er = anr, ei = ani;
            bf16x8 vrh, vrl, vih, vil;
            #pragma unroll
            for (int j = 0; j < 8; ++j) {
                __bf16 h = (__bf16)er;
                vrh[j] = h; vrl[j] = (__bf16)(er - (float)h);
                h = (__bf16)ei;
                vih[j] = h; vil[j] = (__bf16)(ei - (float)h);
                const float nr = er * r1c + ei * r1s;   // *= e^{-i*kvm}
                const float ni = ei * r1c - er * r1s;
                er = nr; ei = ni;
            }
            *(bf16x8*)&sArh[bu][ao] = vrh;
            *(bf16x8*)&sArl[bu][ao] = vrl;
            *(bf16x8*)&sAih[bu][ao] = vih;
            *(bf16x8*)&sAil[bu][ao] = vil;
            const float nr = anr * r32c + ani * r32s;   // anchor *= rot32
            const float ni = ani * r32c - anr * r32s;
            anr = nr; ani = ni;
        }
        // B: img[b, y-octets, x=bx] -> hi/lo, window layout
        #pragma unroll
        for (int oo = 0; oo < 2; ++oo) {
            const int oct = bhalf * 2 + oo;
            bf16x8 bh, bl;
            #pragma unroll
            for (int j = 0; j < 8; ++j) {
                const float v = imgb[(y0 + oct * 8 + j) * NPIX];
                const __bf16 h = (__bf16)v;
                bh[j] = h; bl[j] = (__bf16)(v - (float)h);
            }
            const int bo = WIDX(bx, oct);
            *(bf16x8*)&sBh[bu][bo] = bh;
            *(bf16x8*)&sBl[bu][bo] = bl;
        }
    };

    stage(0, 0);
    __syncthreads();

    for (int k = 0; k < NPIX / KC; ++k) {
        const int cur = k & 1;
        if (k < NPIX / KC - 1)
            stage((k + 1) * KC, 1 - cur);   // fill other buffer (overlaps MFMA
                                            // of other waves in this iter)
        // ---- MFMA chunk k from buffer cur: wave w owns A-rows [16w,16w+16)
        const int aro = WIDX(w * 16 + ln15, q);
        const bf16x8 ah0 = *(const bf16x8*)&sArh[cur][aro];
        const bf16x8 al0 = *(const bf16x8*)&sArl[cur][aro];
        const bf16x8 ah1 = *(const bf16x8*)&sAih[cur][aro];
        const bf16x8 al1 = *(const bf16x8*)&sAil[cur][aro];

        #pragma unroll
        for (int ct = 0; ct < 16; ++ct) {
            const int bro = WIDX(ct * 16 + ln15, q);
            const bf16x8 bh = *(const bf16x8*)&sBh[cur][bro];
            const bf16x8 bl = *(const bf16x8*)&sBl[cur][bro];
            acc[0][ct] = __builtin_amdgcn_mfma_f32_16x16x32_bf16(ah0, bh, acc[0][ct], 0, 0, 0);
            acc[0][ct] = __builtin_amdgcn_mfma_f32_16x16x32_bf16(ah0, bl, acc[0][ct], 0, 0, 0);
            acc[0][ct] = __builtin_amdgcn_mfma_f32_16x16x32_bf16(al0, bh, acc[0][ct], 0, 0, 0);
            acc[1][ct] = __builtin_amdgcn_mfma_f32_16x16x32_bf16(ah1, bh, acc[1][ct], 0, 0, 0);
            acc[1][ct] = __builtin_amdgcn_mfma_f32_16x16x32_bf16(ah1, bl, acc[1][ct], 0, 0, 0);
            acc[1][ct] = __builtin_amdgcn_mfma_f32_16x16x32_bf16(al1, bh, acc[1][ct], 0, 0, 0);
        }
        __syncthreads();   // protects buf[cur] (rewritten in iter k+1's stage)
    }

    // ---- fused stage 2 (in-wave): kdata[b,m] = sum_x tmp[m,x] * Eu[m,x]
    // C layout: col(x within tile) = ln15, row(m within tile) = 4*q + r
    #pragma unroll
    for (int r = 0; r < 4; ++r) {
        const int m = m0 + w * 16 + q * 4 + r;
        const float ku = ktraj[MM + m];
        float s0, c0, s16, c16;
        sincosf(red2pi(ku, (float)(ln15 - 128)), &s0, &c0);
        sincosf(red2pi(ku, 16.0f), &s16, &c16);
        float er = c0, ei = -s0;       // Eu at x = ln15 - 128, step +16 per ct
        float sr = 0.f, si = 0.f;
        #pragma unroll
        for (int ct = 0; ct < 16; ++ct) {
            const float tr = acc[0][ct][r];
            const float ti = acc[1][ct][r];
            sr = fmaf(tr, er, fmaf(-ti, ei, sr));
            si = fmaf(tr, ei, fmaf(ti, er, si));
            const float nr = er * c16 + ei * s16;   // *= e^{-i*ku*16}
            const float ni = ei * c16 - er * s16;
            er = nr; ei = ni;
        }
        // reduce over the 16 lanes of this quad (masks <16 stay in-quad)
        #pragma unroll
        for (int off = 8; off >= 1; off >>= 1) {
            sr += __shfl_xor(sr, off);
            si += __shfl_xor(si, off);
        }
        if (ln15 == 0) {
            const float pr = pulsefac[m];
            const float pi = pulsefac[MM + m];
            const float vr = sr * pr - si * pi;
            const float vi = sr * pi + si * pr;
            out[b * 2 * MM + m]      = vr;
            out[b * 2 * MM + MM + m] = vi;
            out[VISAMP_OFF + b * MM + m] = sqrtf(vr * vr + vi * vi + EPSF);
        }
    }
}

// polynomial atan2 (A&S 4.4.49, err <= ~1e-5 rad), fully predicated
__device__ __forceinline__ float fast_atan2f(float y, float x)
{
    const float ax = fabsf(x), ay = fabsf(y);
    const float mx = fmaxf(ax, ay), mn = fminf(ax, ay);
    const float a  = mn / fmaxf(mx, 1e-37f);
    const float s  = a * a;
    float r = 0.0208351f;
    r = fmaf(r, s, -0.0851330f);
    r = fmaf(r, s,  0.1801410f);
    r = fmaf(r, s, -0.3302995f);
    r = fmaf(r, s,  0.9998660f);
    r *= a;
    r = (ay > ax) ? (1.57079632679f - r) : r;
    r = (x < 0.0f) ? (3.14159265359f - r) : r;
    return (y < 0.0f) ? -r : r;
}

// fused cphase + logcamp. Each block serves ONE batch (NCP % 256 == 0):
// stage that batch's vis (64 KB) into LDS, scatters hit LDS.
__global__ __launch_bounds__(256)
void gather_fused(const float* __restrict__ vis,
                  const float* __restrict__ sign,
                  const int* __restrict__ cind,
                  const int* __restrict__ caind,
                  float* __restrict__ out)
{
    __shared__ float sv[2 * MM];      // 64 KB: [0,MM)=re, [MM,2MM)=im

    const int i = blockIdx.x * 256 + threadIdx.x;
    const int b = i / NCP;
    const int n = i - b * NCP;

    {
        const float4* g4 = (const float4*)(vis + b * 2 * MM);
        float4* s4 = (float4*)sv;
        #pragma unroll
        for (int j = 0; j < (2 * MM / 4) / 256; ++j)
            s4[j * 256 + threadIdx.x] = g4[j * 256 + threadIdx.x];
    }
    __syncthreads();

    float cp = 0.f;
    #pragma unroll
    for (int k = 0; k < 3; ++k) {
        const int m = cind[k * NCP + n];
        cp += sign[k * NCP + n] * fast_atan2f(sv[MM + m], sv[m]);
    }
    out[CPH_OFF + i] = cp * 57.29577951308232f;   // 180/pi

    // logcamp = 0.5*log((p1*p2)/(p3*p4)), p = vr^2+vi^2+eps — one log call
    float p[4];
    #pragma unroll
    for (int k = 0; k < 4; ++k) {
        const int m = caind[k * NCA + n];
        const float vr = sv[m];
        const float vi = sv[MM + m];
        p[k] = vr * vr + vi * vi + EPSF;
    }
    out[LCA_OFF + i] = 0.5f * __logf((p[0] * p[1]) / (p[2] * p[3]));
}

extern "C" void kernel_launch(void* const* d_in, const int* in_sizes, int n_in,
                              void* d_out, int out_size, void* d_ws, size_t ws_size,
                              hipStream_t stream)
{
    const float* images   = (const float*)d_in[0];
    const float* ktraj    = (const float*)d_in[1];
    const float* pulsefac = (const float*)d_in[2];
    const float* csign    = (const float*)d_in[3];
    const int*   cind     = (const int*)d_in[4];
    const int*   caind    = (const int*)d_in[5];
    float* out = (float*)d_out;

    dim3 grid(MM / TMB, BB);
    nufft_vis_mfma<<<grid, NT, 0, stream>>>(images, ktraj, pulsefac, out);
    gather_fused<<<BB * NCP / 256, 256, 0, stream>>>(out, csign, cind, caind, out);
}

// Round 19
// 115.452 us; speedup vs baseline: 1.1575x; 1.1575x over previous
//
#include <hip/hip_runtime.h>
#include <cmath>

#define BB   8
#define NPIX 256
#define MM   8192
#define NCP  24576
#define NCA  24576
#define EPSF 1e-16f

#define KC   32    // K-chunk (y's per chunk) = one MFMA K-step
#define TMB  128   // m's per block
#define NT   512   // threads per block (8 waves)

// ---- d_out layout (floats)
#define VIS_OFF    0
#define VISAMP_OFF (BB * 2 * MM)            // 131072
#define CPH_OFF    (VISAMP_OFF + BB * MM)   // 196608
#define LCA_OFF    (CPH_OFF + BB * NCP)     // 393216

typedef __bf16 bf16x8 __attribute__((ext_vector_type(8)));
typedef float  f32x4  __attribute__((ext_vector_type(4)));

// Window layout: element (row,k) -> (row>>4)*512 + (k>>3)*128 + (row&15)*8
// + (k&7). Staging writes and fragment reads: 16 B lane stride within each
// 16-lane phase -> 2-way bank aliasing only (free, m136).
// SESSION RULES (hard-won):
//  - no cross-kernel dataflow through d_ws (R5/R6); d_out is proven.
//  - acc = 128 AGPR + ~124 VGPR: needs the 256-reg budget (launch_bounds
//    2nd arg = 2). Tighter caps spill catastrophically (R8/R10).
//    WRITE_SIZE is the spill tripwire (768 KB = clean).
//  - NUMERICS: full 3-term split mandatory (R12: 2-term -> cphase 361 deg).
//  - PIPELINING CLOSED: double-buffered LDS + 1 barrier/chunk REGRESSED
//    58->80 us (R18: lgkmcnt drains staging ds_writes before MFMA ds_reads;
//    matches learn_hip m99/m131-m141 plateau). Keep single-buffer 2-barrier.
//  - residual ~57 us outside the vis kernel is harness-fixed (invariant
//    across gather rewrites R9/R11/R13); vis is the only lever.
#define WIDX(row, k8) (((row) >> 4) * 512 + (k8) * 128 + ((row) & 15) * 8)

// range reduction: theta == k*n (mod 2pi) in [-pi,pi] (keeps sincosf fast).
__device__ __forceinline__ float red2pi(float k, float n)
{
    const double t = (double)k * (double)n * 0.15915494309189535;  // /(2pi)
    const double f = t - rint(t);
    return (float)(f * 6.283185307179586);
}

// Block: 128 m's x 256 x's x 1 batch, 8 waves. Ev via rotor recurrences.
// 3-term split MFMA (hh, hl, lh) per plane.
__global__ __launch_bounds__(NT, 2)
void nufft_vis_mfma(const float* __restrict__ images,
                    const float* __restrict__ ktraj,
                    const float* __restrict__ pulsefac,
                    float* __restrict__ out)
{
    __shared__ __align__(16) __bf16 sArh[TMB * KC];   // 8 KB  Evr hi
    __shared__ __align__(16) __bf16 sArl[TMB * KC];   // 8 KB  Evr lo
    __shared__ __align__(16) __bf16 sAih[TMB * KC];   // 8 KB  Evi hi
    __shared__ __align__(16) __bf16 sAil[TMB * KC];   // 8 KB  Evi lo
    __shared__ __align__(16) __bf16 sBh[NPIX * KC];   // 16 KB img hi
    __shared__ __align__(16) __bf16 sBl[NPIX * KC];   // 16 KB img lo

    const int tid  = threadIdx.x;
    const int m0   = blockIdx.x * TMB;
    const int b    = blockIdx.y;
    const int lane = tid & 63;
    const int w    = tid >> 6;        // wave 0..7
    const int ln15 = lane & 15;
    const int q    = lane >> 4;       // k-octet 0..3

    // A staging: thread stages Ev row = tid&127, k-octet = tid>>7.
    const int arow = tid & 127;
    const int aoct = tid >> 7;        // 0..3
    const float kvm = ktraj[m0 + arow];
    float r1s, r1c, r32s, r32c, as_, ac_;
    sincosf(kvm, &r1s, &r1c);                          // rot1: |kvm| <= pi
    sincosf(red2pi(kvm, 32.0f), &r32s, &r32c);         // rot32
    sincosf(red2pi(kvm, (float)(aoct * 8 - 128)), &as_, &ac_);  // anchor @ y0=0
    float anr = ac_, ani = -as_;
    const int ao = WIDX(arow, aoct);

    // B staging: x = tid&255, y-octet pair = (tid>>8)*2 .. +1
    const int bx    = tid & 255;
    const int bhalf = tid >> 8;       // 0..1
    const float* imgb = images + b * NPIX * NPIX + bx;

    f32x4 acc[2][16];                 // [0]=real plane, [1]=imag plane
    #pragma unroll
    for (int rt = 0; rt < 2; ++rt)
        #pragma unroll
        for (int ct = 0; ct < 16; ++ct)
            acc[rt][ct] = (f32x4){0.f, 0.f, 0.f, 0.f};

    for (int y0 = 0; y0 < NPIX; y0 += KC) {
        // ---- stage A: Ev[m0+arow, y0+8*aoct .. +8) via anchor + rot1
        {
            float er = anr, ei = ani;   // Ev = exp(-i*kv*(y-128))
            bf16x8 vrh, vrl, vih, vil;
            #pragma unroll
            for (int j = 0; j < 8; ++j) {
                __bf16 h = (__bf16)er;
                vrh[j] = h; vrl[j] = (__bf16)(er - (float)h);
                h = (__bf16)ei;
                vih[j] = h; vil[j] = (__bf16)(ei - (float)h);
                const float nr = er * r1c + ei * r1s;   // *= e^{-i*kvm}
                const float ni = ei * r1c - er * r1s;
                er = nr; ei = ni;
            }
            *(bf16x8*)&sArh[ao] = vrh;
            *(bf16x8*)&sArl[ao] = vrl;
            *(bf16x8*)&sAih[ao] = vih;
            *(bf16x8*)&sAil[ao] = vil;
            // advance anchor to next chunk: *= e^{-i*kvm*32}
            const float nr = anr * r32c + ani * r32s;
            const float ni = ani * r32c - anr * r32s;
            anr = nr; ani = ni;
        }
        // ---- stage B: img[b, y-octets, x=bx] -> hi/lo, window layout
        #pragma unroll
        for (int oo = 0; oo < 2; ++oo) {
            const int oct = bhalf * 2 + oo;
            bf16x8 bh, bl;
            #pragma unroll
            for (int j = 0; j < 8; ++j) {
                const float v = imgb[(y0 + oct * 8 + j) * NPIX];
                const __bf16 h = (__bf16)v;
                bh[j] = h; bl[j] = (__bf16)(v - (float)h);
            }
            const int bo = WIDX(bx, oct);
            *(bf16x8*)&sBh[bo] = bh;
            *(bf16x8*)&sBl[bo] = bl;
        }
        __syncthreads();

        // ---- MFMA: wave w owns A-rows [16w, 16w+16)
        const int aro = WIDX(w * 16 + ln15, q);
        const bf16x8 ah0 = *(const bf16x8*)&sArh[aro];
        const bf16x8 al0 = *(const bf16x8*)&sArl[aro];
        const bf16x8 ah1 = *(const bf16x8*)&sAih[aro];
        const bf16x8 al1 = *(const bf16x8*)&sAil[aro];

        #pragma unroll
        for (int ct = 0; ct < 16; ++ct) {
            const int bro = WIDX(ct * 16 + ln15, q);
            const bf16x8 bh = *(const bf16x8*)&sBh[bro];
            const bf16x8 bl = *(const bf16x8*)&sBl[bro];
            acc[0][ct] = __builtin_amdgcn_mfma_f32_16x16x32_bf16(ah0, bh, acc[0][ct], 0, 0, 0);
            acc[0][ct] = __builtin_amdgcn_mfma_f32_16x16x32_bf16(ah0, bl, acc[0][ct], 0, 0, 0);
            acc[0][ct] = __builtin_amdgcn_mfma_f32_16x16x32_bf16(al0, bh, acc[0][ct], 0, 0, 0);
            acc[1][ct] = __builtin_amdgcn_mfma_f32_16x16x32_bf16(ah1, bh, acc[1][ct], 0, 0, 0);
            acc[1][ct] = __builtin_amdgcn_mfma_f32_16x16x32_bf16(ah1, bl, acc[1][ct], 0, 0, 0);
            acc[1][ct] = __builtin_amdgcn_mfma_f32_16x16x32_bf16(al1, bh, acc[1][ct], 0, 0, 0);
        }
        __syncthreads();
    }

    // ---- fused stage 2 (in-wave): kdata[b,m] = sum_x tmp[m,x] * Eu[m,x]
    // C layout: col(x within tile) = ln15, row(m within tile) = 4*q + r
    #pragma unroll
    for (int r = 0; r < 4; ++r) {
        const int m = m0 + w * 16 + q * 4 + r;
        const float ku = ktraj[MM + m];
        float s0, c0, s16, c16;
        sincosf(red2pi(ku, (float)(ln15 - 128)), &s0, &c0);
        sincosf(red2pi(ku, 16.0f), &s16, &c16);
        float er = c0, ei = -s0;       // Eu at x = ln15 - 128, step +16 per ct
        float sr = 0.f, si = 0.f;
        #pragma unroll
        for (int ct = 0; ct < 16; ++ct) {
            const float tr = acc[0][ct][r];
            const float ti = acc[1][ct][r];
            sr = fmaf(tr, er, fmaf(-ti, ei, sr));
            si = fmaf(tr, ei, fmaf(ti, er, si));
            const float nr = er * c16 + ei * s16;   // *= e^{-i*ku*16}
            const float ni = ei * c16 - er * s16;
            er = nr; ei = ni;
        }
        // reduce over the 16 lanes of this quad (masks <16 stay in-quad)
        #pragma unroll
        for (int off = 8; off >= 1; off >>= 1) {
            sr += __shfl_xor(sr, off);
            si += __shfl_xor(si, off);
        }
        if (ln15 == 0) {
            const float pr = pulsefac[m];
            const float pi = pulsefac[MM + m];
            const float vr = sr * pr - si * pi;
            const float vi = sr * pi + si * pr;
            out[b * 2 * MM + m]      = vr;
            out[b * 2 * MM + MM + m] = vi;
            out[VISAMP_OFF + b * MM + m] = sqrtf(vr * vr + vi * vi + EPSF);
        }
    }
}

// polynomial atan2 (A&S 4.4.49, err <= ~1e-5 rad), fully predicated
__device__ __forceinline__ float fast_atan2f(float y, float x)
{
    const float ax = fabsf(x), ay = fabsf(y);
    const float mx = fmaxf(ax, ay), mn = fminf(ax, ay);
    const float a  = mn / fmaxf(mx, 1e-37f);
    const float s  = a * a;
    float r = 0.0208351f;
    r = fmaf(r, s, -0.0851330f);
    r = fmaf(r, s,  0.1801410f);
    r = fmaf(r, s, -0.3302995f);
    r = fmaf(r, s,  0.9998660f);
    r *= a;
    r = (ay > ax) ? (1.57079632679f - r) : r;
    r = (x < 0.0f) ? (3.14159265359f - r) : r;
    return (y < 0.0f) ? -r : r;
}

// fused cphase + logcamp. Each block serves ONE batch (NCP % 256 == 0):
// stage that batch's vis (64 KB) into LDS, scatters hit LDS.
__global__ __launch_bounds__(256)
void gather_fused(const float* __restrict__ vis,
                  const float* __restrict__ sign,
                  const int* __restrict__ cind,
                  const int* __restrict__ caind,
                  float* __restrict__ out)
{
    __shared__ float sv[2 * MM];      // 64 KB: [0,MM)=re, [MM,2MM)=im

    const int i = blockIdx.x * 256 + threadIdx.x;
    const int b = i / NCP;
    const int n = i - b * NCP;

    {
        const float4* g4 = (const float4*)(vis + b * 2 * MM);
        float4* s4 = (float4*)sv;
        #pragma unroll
        for (int j = 0; j < (2 * MM / 4) / 256; ++j)
            s4[j * 256 + threadIdx.x] = g4[j * 256 + threadIdx.x];
    }
    __syncthreads();

    float cp = 0.f;
    #pragma unroll
    for (int k = 0; k < 3; ++k) {
        const int m = cind[k * NCP + n];
        cp += sign[k * NCP + n] * fast_atan2f(sv[MM + m], sv[m]);
    }
    out[CPH_OFF + i] = cp * 57.29577951308232f;   // 180/pi

    // logcamp = 0.5*log((p1*p2)/(p3*p4)), p = vr^2+vi^2+eps — one log call
    float p[4];
    #pragma unroll
    for (int k = 0; k < 4; ++k) {
        const int m = caind[k * NCA + n];
        const float vr = sv[m];
        const float vi = sv[MM + m];
        p[k] = vr * vr + vi * vi + EPSF;
    }
    out[LCA_OFF + i] = 0.5f * __logf((p[0] * p[1]) / (p[2] * p[3]));
}

extern "C" void kernel_launch(void* const* d_in, const int* in_sizes, int n_in,
                              void* d_out, int out_size, void* d_ws, size_t ws_size,
                              hipStream_t stream)
{
    const float* images   = (const float*)d_in[0];
    const float* ktraj    = (const float*)d_in[1];
    const float* pulsefac = (const float*)d_in[2];
    const float* csign    = (const float*)d_in[3];
    const int*   cind     = (const int*)d_in[4];
    const int*   caind    = (const int*)d_in[5];
    float* out = (float*)d_out;

    dim3 grid(MM / TMB, BB);
    nufft_vis_mfma<<<grid, NT, 0, stream>>>(images, ktraj, pulsefac, out);
    gather_fused<<<BB * NCP / 256, 256, 0, stream>>>(out, csign, cind, caind, out);
}